// Round 14
// baseline (270.071 us; speedup 1.0000x reference)
//
#include <hip/hip_runtime.h>
#include <math.h>

#define NTOK 16384
#define DDIM 512
#define MDIM 1024
#define NEXP 8
#define BKW 32       // K-step in shorts; LDS row = 64 bytes
#define TMAX 264     // max row-tiles across experts: 256 + 8 partial

typedef __attribute__((ext_vector_type(8))) short short8;
typedef __attribute__((ext_vector_type(4))) float floatx4;

__device__ inline unsigned short f2bf(float f){
  union { float f; unsigned int u; } v; v.f = f;
  unsigned int u = v.u;
  u += ((u >> 16) & 1u) + 0x7fffu;   // round-to-nearest-even
  return (unsigned short)(u >> 16);
}

__device__ inline float bf2f(unsigned short s){
  union { unsigned int u; float f; } v;
  v.u = ((unsigned int)s) << 16;
  return v.f;
}

// branch-free erf-based gelu, A&S 7.1.26 (|erf err| <= 1.5e-7)
__device__ inline float gelu_fast(float x){
  float u = x * 0.70710678118654752f;
  float a = fabsf(u);
  float t = __builtin_amdgcn_rcpf(fmaf(0.3275911f, a, 1.0f));
  float p = fmaf(1.061405429f, t, -1.453152027f);
  p = fmaf(p, t, 1.421413741f);
  p = fmaf(p, t, -0.284496736f);
  p = fmaf(p, t, 0.254829592f);
  p = p * t;
  float e = __expf(-u * u);
  float erfa = fmaf(-p, e, 1.0f);         // erf(|u|)
  float erfu = copysignf(erfa, u);
  return 0.5f * x * (1.0f + erfu);
}

// async global -> LDS, 16 bytes per lane; lds base must be wave-uniform
__device__ __forceinline__ void gload16(const unsigned short* g, unsigned short* l){
  __builtin_amdgcn_global_load_lds(
      (const __attribute__((address_space(1))) void*)g,
      (__attribute__((address_space(3))) void*)l,
      16, 0, 0);
}

// ---------------- fused prep: W1/W2 transpose+bf16 conv + counts/imp/rank init ----
// grid (32,16,16): z<8 -> W1 (R=512,C=1024)   z>=8 -> W2 (R=1024,C=512)

__global__ void prep_kernel(const float* __restrict__ W1, const float* __restrict__ W2,
                            unsigned short* __restrict__ w1t, unsigned short* __restrict__ w2t,
                            int* __restrict__ counts, float* __restrict__ imp,
                            int* __restrict__ rank){
  __shared__ float tile[32][33];
  int z = blockIdx.z;
  if (z == 0 && blockIdx.x == 0 && blockIdx.y == 0){
    int flat = threadIdx.y * 32 + threadIdx.x;
    if (flat < NEXP){ counts[flat] = 0; imp[flat] = 0.0f; rank[flat] = 0; }
  }
  const float* in; unsigned short* out; int R, C, c0, r0, e;
  if (z < 8){ e = z;     in = W1; out = w1t; R = DDIM; C = MDIM; c0 = blockIdx.x << 5; r0 = blockIdx.y << 5; }
  else      { e = z - 8; in = W2; out = w2t; R = MDIM; C = DDIM; c0 = blockIdx.y << 5; r0 = blockIdx.x << 5; }
  const float* src = in + (size_t)e * R * C;
  unsigned short* dst = out + (size_t)e * R * C;
  int tc = threadIdx.x;   // 0..31
  int tr = threadIdx.y;   // 0..7
  #pragma unroll
  for (int i = 0; i < 32; i += 8)
    tile[tr + i][tc] = src[(size_t)(r0 + tr + i) * C + c0 + tc];
  __syncthreads();
  #pragma unroll
  for (int i = 0; i < 32; i += 8)
    dst[(size_t)(c0 + tr + i) * R + r0 + tc] = f2bf(tile[tc][tr + i]);
}

// ---------------- fused gating + x->bf16 conversion ----------------

__global__ __launch_bounds__(256)
void gating_kernel(const float* __restrict__ x,
                   const float* __restrict__ wg,
                   unsigned short* __restrict__ xb,
                   int* __restrict__ tok_e, float* __restrict__ tok_g,
                   int* __restrict__ counts, float* __restrict__ imp){
  __shared__ int   lcnt[NEXP];
  __shared__ float limp[NEXP];
  int t = threadIdx.x;
  if (t < NEXP){ lcnt[t] = 0; limp[t] = 0.0f; }
  __syncthreads();

  int wave = t >> 6;
  int lane = t & 63;

  for (int it = 0; it < 4; it++){
    int n = blockIdx.x * 16 + it * 4 + wave;

    const float4* xp = (const float4*)(x + (size_t)n * DDIM + lane * 8);
    float4 a = xp[0], b = xp[1];
    float xv[8] = {a.x, a.y, a.z, a.w, b.x, b.y, b.z, b.w};

    short8 xo;
    #pragma unroll
    for (int j = 0; j < 8; j++) xo[j] = (short)f2bf(xv[j]);
    *(short8*)(xb + (size_t)n * DDIM + lane * 8) = xo;

    double acc[NEXP];
    #pragma unroll
    for (int e = 0; e < NEXP; e++) acc[e] = 0.0;
    #pragma unroll
    for (int j = 0; j < 8; j++){
      const float* wr = wg + (size_t)(lane * 8 + j) * NEXP;
      #pragma unroll
      for (int e = 0; e < NEXP; e++) acc[e] += (double)xv[j] * (double)wr[e];
    }
    #pragma unroll
    for (int off = 32; off >= 1; off >>= 1){
      #pragma unroll
      for (int e = 0; e < NEXP; e++) acc[e] += __shfl_xor(acc[e], off);
    }
    if (lane == 0){
      int i0 = -1, i1 = -1;
      double l0 = -1e300, l1 = -1e300;
      #pragma unroll
      for (int e = 0; e < NEXP; e++){
        double v = acc[e];
        if (v > l0){ l1 = l0; i1 = i0; l0 = v; i0 = e; }
        else if (v > l1){ l1 = v; i1 = e; }
      }
      float ex = expf((float)(l1 - l0));
      float g0 = 1.0f / (1.0f + ex);
      float g1 = ex / (1.0f + ex);
      tok_e[n * 2]     = i0; tok_e[n * 2 + 1] = i1;
      tok_g[n * 2]     = g0; tok_g[n * 2 + 1] = g1;
      atomicAdd(&lcnt[i0], 1); atomicAdd(&lcnt[i1], 1);
      atomicAdd(&limp[i0], g0); atomicAdd(&limp[i1], g1);
    }
  }
  __syncthreads();
  if (t < NEXP){
    atomicAdd(&counts[t], lcnt[t]);
    atomicAdd(&imp[t], limp[t]);
  }
}

// ---------------- scatter + fused loss/offsets publication ----------------
// slot_tok2[slot] = 2n+k (inverse permutation) -> gemm2 stores O token-major,
// combine becomes pure streaming.

__global__ __launch_bounds__(256)
void scatter_kernel(const int* __restrict__ counts,
                    const float* __restrict__ imp,
                    const int* __restrict__ tok_e,
                    int* __restrict__ rank,
                    int* __restrict__ offsets_g, int* __restrict__ tile_pre_g,
                    int* __restrict__ btok, int* __restrict__ slot_tok2,
                    float* __restrict__ out_loss){
  __shared__ int lcnt[NEXP];
  __shared__ int lbase[NEXP];
  int t = threadIdx.x;
  if (t < NEXP) lcnt[t] = 0;
  __syncthreads();

  int n = blockIdx.x * 256 + t;
  int e0 = tok_e[n * 2], e1 = tok_e[n * 2 + 1];
  int r0 = atomicAdd(&lcnt[e0], 1);
  int r1 = atomicAdd(&lcnt[e1], 1);
  __syncthreads();
  if (t < NEXP){
    int offacc = 0;
    #pragma unroll
    for (int e = 0; e < NEXP; e++){ int c = counts[e]; if (e < t) offacc += c; }
    lbase[t] = offacc + atomicAdd(&rank[t], lcnt[t]);
  }
  __syncthreads();
  int s0 = lbase[e0] + r0;
  int s1 = lbase[e1] + r1;
  btok[s0] = n;
  btok[s1] = n;
  slot_tok2[s0] = n * 2;
  slot_tok2[s1] = n * 2 + 1;

  // block 0, wave 0: loss + publish offsets/tile_pre
  if (blockIdx.x == 0 && t < 64){
    int l = t;
    int   c  = (l < NEXP) ? counts[l] : 0;
    float im = (l < NEXP) ? imp[l]    : 0.0f;
    int   tl = (c + 127) >> 7;
    int poff = 0, ptl = 0, tot = 0, tott = 0;
    double si = 0, si2 = 0, sl = 0, sl2 = 0;
    #pragma unroll
    for (int e = 0; e < NEXP; e++){
      int   ce = __shfl(c, e);
      int   te = __shfl(tl, e);
      float ie = __shfl(im, e);
      if (e < l){ poff += ce; ptl += te; }
      tot += ce; tott += te;
      si += (double)ie; si2 += (double)ie * ie;
      sl += (double)ce; sl2 += (double)ce * ce;
    }
    if (l < NEXP){ offsets_g[l] = poff; tile_pre_g[l] = ptl; }
    if (l == 0){
      offsets_g[NEXP] = tot; tile_pre_g[NEXP] = tott;
      double mi = si / 8.0, ml = sl / 8.0;
      double vi = (si2 - 8.0 * mi * mi) / 7.0;
      double vl = (sl2 - 8.0 * ml * ml) / 7.0;
      *out_loss = (float)(0.01 * (vi / (mi * mi + 1e-10) + vl / (ml * ml + 1e-10)));
    }
  }
}

// ------- expert GEMMs: 128x128 tile, 8 waves, 2-buffer early-stage pipeline -------
// (R12 experiment, re-isolated: __launch_bounds__ restored to (512,6) — the exact
// attribute that compiled+ran R5-R11. (512,8)'s forced 64-VGPR budget was the one
// never-validated attribute in the twice-failed R12/R13 binary. Occupancy comes
// from actual resources: VGPR~40, LDS 32KB -> 4 blocks/CU reachable regardless.)
// Step k: {STAGE(k+1 -> buf^1) issued FIRST; ds_read frags(buf k&1); MFMA;
// vmcnt(0); s_barrier}. Stage has the whole ds_read+MFMA phase in flight;
// cross-block phase offset (m114) hides the end-of-step drain.
// RAW: vmcnt(0)+barrier end of step k -> STAGE(k+1) visible at step k+1.
// WAR: every wave's reads of buf^1 (step k-1) completed before it passed
// barrier k-1; STAGE at step k is after that barrier.
// Unroll, setprio, XOR chunk-swizzle both-sides, contiguous-tt XCD map kept.

__global__ __launch_bounds__(512, 6)
void gemm1_kernel(const unsigned short* __restrict__ xb,
                  const unsigned short* __restrict__ w1t,   // [E][M][D]
                  const float* __restrict__ b1,             // [E][M]
                  const int* __restrict__ offsets,
                  const int* __restrict__ tile_pre,
                  const int* __restrict__ btok,
                  unsigned short* __restrict__ H){          // [slot][M]
  int b = blockIdx.x;                  // grid = 8*TMAX
  int L = (b & 7) * TMAX + (b >> 3);   // contiguous logical chunk per XCD
  int ct = L & 7;                      // column tile 0..7
  int tt = L >> 3;                     // row tile
  if (tt >= tile_pre[NEXP]) return;
  int e = 0;
  while (tt >= tile_pre[e + 1]) e++;
  int rt = tt - tile_pre[e];
  int off = offsets[e];
  int cnt = offsets[e + 1] - off;
  int r0 = rt << 7;

  __shared__ unsigned short As[2 * 128 * BKW];   // 16KB
  __shared__ unsigned short Bs[2 * 128 * BKW];   // 16KB

  int t = threadIdx.x;
  int w = t >> 6;                         // 0..7
  int l = t & 63;
  int g = (l & 3) ^ ((l >> 3) & 3);       // pre-swizzled source chunk

  const unsigned short* apt;
  {
    int ra = r0 + w * 16 + (l >> 2);  if (ra >= cnt) ra = cnt - 1;
    apt = xb + (size_t)btok[off + ra] * DDIM + g * 8;
  }
  const unsigned short* bpt = w1t + ((size_t)e * MDIM + (ct << 7) + w * 16 + (l >> 2)) * DDIM + g * 8;

  int wr = (w >> 1) << 5;                 // 0,32,64,96
  int wc = (w & 1) << 6;                  // 0,64
  int lm = l & 15;
  int lq = l >> 4;
  int swz = (lm >> 1) & 3;

  int aoff[2], boff[4];
  #pragma unroll
  for (int i = 0; i < 2; i++) aoff[i] = (wr + i * 16 + lm) * BKW + ((lq ^ swz) << 3);
  #pragma unroll
  for (int j = 0; j < 4; j++) boff[j] = (wc + j * 16 + lm) * BKW + ((lq ^ swz) << 3);

  floatx4 acc[2][4] = {};

  #define STAGE1(K0, CB) {                                   \
    gload16(apt + (K0), As + (CB) * 4096 + w * 512);         \
    gload16(bpt + (K0), Bs + (CB) * 4096 + w * 512);         \
  }
  #define READ1(CB) {                                        \
    const unsigned short* Ac = As + (CB) * 4096;             \
    const unsigned short* Bc = Bs + (CB) * 4096;             \
    _Pragma("unroll")                                        \
    for (int i = 0; i < 2; i++) af[i]  = *(const short8*)(Ac + aoff[i]); \
    _Pragma("unroll")                                        \
    for (int j = 0; j < 4; j++) bfr[j] = *(const short8*)(Bc + boff[j]); \
  }
  #define MFMA1 {                                            \
    _Pragma("unroll")                                        \
    for (int i = 0; i < 2; i++)                              \
      _Pragma("unroll")                                      \
      for (int j = 0; j < 4; j++)                            \
        acc[i][j] = __builtin_amdgcn_mfma_f32_16x16x32_bf16(af[i], bfr[j], acc[i][j], 0, 0, 0); \
  }
  #define WAITBAR {                                          \
    asm volatile("s_waitcnt vmcnt(0)" ::: "memory");         \
    __builtin_amdgcn_sched_barrier(0);                       \
    __builtin_amdgcn_s_barrier();                            \
    __builtin_amdgcn_sched_barrier(0);                       \
  }

  const int NK = DDIM / BKW;             // 16
  STAGE1(0, 0);
  WAITBAR;                               // buf0 ready
  #pragma unroll
  for (int k = 0; k < NK; k++){
    short8 af[2], bfr[4];
    if (k + 1 < NK) STAGE1((k + 1) * BKW, (k + 1) & 1);   // issue first: overlaps step
    READ1(k & 1);
    __builtin_amdgcn_s_setprio(1);
    MFMA1;
    __builtin_amdgcn_s_setprio(0);
    if (k + 1 < NK){ WAITBAR; }          // drain STAGE(k+1); barrier
    // k == NK-1: no barrier
  }
  #undef STAGE1
  #undef READ1
  #undef MFMA1
  #undef WAITBAR

  const float* bias = b1 + e * MDIM + (ct << 7);
  #pragma unroll
  for (int i = 0; i < 2; i++){
    int rbase = wr + i * 16 + lq * 4;
    #pragma unroll
    for (int j = 0; j < 4; j++){
      int cc = wc + j * 16 + lm;
      float bv = bias[cc];
      #pragma unroll
      for (int r = 0; r < 4; r++){
        int row = r0 + rbase + r;
        if (row < cnt){
          float v = acc[i][j][r] + bv;
          H[(size_t)(off + row) * MDIM + (ct << 7) + cc] = f2bf(gelu_fast(v));
        }
      }
    }
  }
}

__global__ __launch_bounds__(512, 6)
void gemm2_kernel(const unsigned short* __restrict__ H,    // [slot][M]
                  const unsigned short* __restrict__ w2t,  // [E][D][M]
                  const float* __restrict__ b2,            // [E][D]
                  const int* __restrict__ offsets,
                  const int* __restrict__ tile_pre,
                  const int* __restrict__ slot_tok2,
                  unsigned short* __restrict__ O){         // [2n+k][D] bf16, token-major
  int b = blockIdx.x;                        // grid = 4*TMAX = 8*(TMAX/2)
  int L = (b & 7) * (TMAX / 2) + (b >> 3);   // contiguous logical chunk per XCD
  int ct = L & 3;                            // column tile 0..3
  int tt = L >> 2;                           // row tile
  if (tt >= tile_pre[NEXP]) return;
  int e = 0;
  while (tt >= tile_pre[e + 1]) e++;
  int rt = tt - tile_pre[e];
  int off = offsets[e];
  int cnt = offsets[e + 1] - off;
  int r0 = rt << 7;

  __shared__ unsigned short As[2 * 128 * BKW];
  __shared__ unsigned short Bs[2 * 128 * BKW];

  int t = threadIdx.x;
  int w = t >> 6;
  int l = t & 63;
  int g = (l & 3) ^ ((l >> 3) & 3);

  const unsigned short* apt;
  {
    int ra = r0 + w * 16 + (l >> 2);  if (ra >= cnt) ra = cnt - 1;
    apt = H + (size_t)(off + ra) * MDIM + g * 8;
  }
  const unsigned short* bpt = w2t + ((size_t)e * DDIM + (ct << 7) + w * 16 + (l >> 2)) * MDIM + g * 8;

  int wr = (w >> 1) << 5;
  int wc = (w & 1) << 6;
  int lm = l & 15;
  int lq = l >> 4;
  int swz = (lm >> 1) & 3;

  int aoff[2], boff[4];
  #pragma unroll
  for (int i = 0; i < 2; i++) aoff[i] = (wr + i * 16 + lm) * BKW + ((lq ^ swz) << 3);
  #pragma unroll
  for (int j = 0; j < 4; j++) boff[j] = (wc + j * 16 + lm) * BKW + ((lq ^ swz) << 3);

  floatx4 acc[2][4] = {};

  #define STAGE2(K0, CB) {                                   \
    gload16(apt + (K0), As + (CB) * 4096 + w * 512);         \
    gload16(bpt + (K0), Bs + (CB) * 4096 + w * 512);         \
  }
  #define READ2(CB) {                                        \
    const unsigned short* Ac = As + (CB) * 4096;             \
    const unsigned short* Bc = Bs + (CB) * 4096;             \
    _Pragma("unroll")                                        \
    for (int i = 0; i < 2; i++) af[i]  = *(const short8*)(Ac + aoff[i]); \
    _Pragma("unroll")                                        \
    for (int j = 0; j < 4; j++) bfr[j] = *(const short8*)(Bc + boff[j]); \
  }
  #define MFMA2 {                                            \
    _Pragma("unroll")                                        \
    for (int i = 0; i < 2; i++)                              \
      _Pragma("unroll")                                      \
      for (int j = 0; j < 4; j++)                            \
        acc[i][j] = __builtin_amdgcn_mfma_f32_16x16x32_bf16(af[i], bfr[j], acc[i][j], 0, 0, 0); \
  }
  #define WAITBAR2 {                                         \
    asm volatile("s_waitcnt vmcnt(0)" ::: "memory");         \
    __builtin_amdgcn_sched_barrier(0);                       \
    __builtin_amdgcn_s_barrier();                            \
    __builtin_amdgcn_sched_barrier(0);                       \
  }

  const int NK = MDIM / BKW;             // 32
  STAGE2(0, 0);
  WAITBAR2;
  #pragma unroll
  for (int k = 0; k < NK; k++){
    short8 af[2], bfr[4];
    if (k + 1 < NK) STAGE2((k + 1) * BKW, (k + 1) & 1);
    READ2(k & 1);
    __builtin_amdgcn_s_setprio(1);
    MFMA2;
    __builtin_amdgcn_s_setprio(0);
    if (k + 1 < NK){ WAITBAR2; }
  }
  #undef STAGE2
  #undef READ2
  #undef MFMA2
  #undef WAITBAR2

  const float* bias = b2 + e * DDIM + (ct << 7);
  #pragma unroll
  for (int i = 0; i < 2; i++){
    int rbase = wr + i * 16 + lq * 4;
    #pragma unroll
    for (int r = 0; r < 4; r++){
      int row = r0 + rbase + r;
      if (row < cnt){
        int t2 = slot_tok2[off + row];     // token-major destination row
        #pragma unroll
        for (int j = 0; j < 4; j++){
          int cc = wc + j * 16 + lm;
          O[(size_t)t2 * DDIM + (ct << 7) + cc] = f2bf(acc[i][j][r] + bias[cc]);
        }
      }
    }
  }
}

// ------- streaming combine: y[n] = g0*O[2n] + g1*O[2n+1], fully sequential -------

__global__ __launch_bounds__(256)
void combine_kernel(const unsigned short* __restrict__ O,
                    const float* __restrict__ tok_g,
                    float* __restrict__ y){
  int wave = threadIdx.x >> 6;
  int lane = threadIdx.x & 63;
  int n = blockIdx.x * 4 + wave;
  float g0 = tok_g[n * 2], g1 = tok_g[n * 2 + 1];
  short8 a = *(const short8*)(O + (size_t)(n * 2)     * DDIM + lane * 8);
  short8 b = *(const short8*)(O + (size_t)(n * 2 + 1) * DDIM + lane * 8);
  float4 o0, o1;
  float* po0 = (float*)&o0;
  float* po1 = (float*)&o1;
  #pragma unroll
  for (int j = 0; j < 4; j++){
    po0[j] = g0 * bf2f((unsigned short)a[j]) + g1 * bf2f((unsigned short)b[j]);
    po1[j] = g0 * bf2f((unsigned short)a[j + 4]) + g1 * bf2f((unsigned short)b[j + 4]);
  }
  float4* yp = (float4*)(y + (size_t)n * DDIM + lane * 8);
  yp[0] = o0;
  yp[1] = o1;
}

// ---------------- launch ----------------

extern "C" void kernel_launch(void* const* d_in, const int* in_sizes, int n_in,
                              void* d_out, int out_size, void* d_ws, size_t ws_size,
                              hipStream_t stream){
  const float* x  = (const float*)d_in[0];
  const float* wg = (const float*)d_in[1];
  const float* W1 = (const float*)d_in[2];
  const float* b1 = (const float*)d_in[3];
  const float* W2 = (const float*)d_in[4];
  const float* b2 = (const float*)d_in[5];
  float* y = (float*)d_out;

  char* ws = (char*)d_ws;
  size_t o = 0;
  auto alloc = [&](size_t bytes)->char*{
    char* p = ws + o;
    o += (bytes + 255) & ~(size_t)255;
    return p;
  };
  unsigned short* xb   = (unsigned short*)alloc((size_t)NTOK * DDIM * 2);
  unsigned short* w1t  = (unsigned short*)alloc((size_t)NEXP * MDIM * DDIM * 2);
  unsigned short* w2t  = (unsigned short*)alloc((size_t)NEXP * DDIM * MDIM * 2);
  unsigned short* H    = (unsigned short*)alloc((size_t)NTOK * 2 * MDIM * 2);
  unsigned short* O    = (unsigned short*)alloc((size_t)NTOK * 2 * DDIM * 2);
  int*   btok     = (int*)  alloc((size_t)NTOK * 2 * 4);
  int*   slot_tok2= (int*)  alloc((size_t)NTOK * 2 * 4);
  int*   tok_e    = (int*)  alloc((size_t)NTOK * 2 * 4);
  float* tok_g    = (float*)alloc((size_t)NTOK * 2 * 4);
  int*   counts   = (int*)  alloc(64);
  float* imp      = (float*)alloc(64);
  int*   rank     = (int*)  alloc(64);
  int*   offsets  = (int*)  alloc(64);
  int*   tile_pre = (int*)  alloc(64);

  hipLaunchKernelGGL(prep_kernel, dim3(32, 16, 16), dim3(32, 8), 0, stream,
                     W1, W2, w1t, w2t, counts, imp, rank);
  hipLaunchKernelGGL(gating_kernel, dim3(NTOK / 16), dim3(256), 0, stream,
                     x, wg, xb, tok_e, tok_g, counts, imp);
  hipLaunchKernelGGL(scatter_kernel, dim3(NTOK / 256), dim3(256), 0, stream,
                     counts, imp, tok_e, rank, offsets, tile_pre,
                     btok, slot_tok2, y + (size_t)NTOK * DDIM);
  hipLaunchKernelGGL(gemm1_kernel, dim3(TMAX * 8), dim3(512), 0, stream,
                     xb, w1t, b1, offsets, tile_pre, btok, H);
  hipLaunchKernelGGL(gemm2_kernel, dim3(TMAX * 4), dim3(512), 0, stream,
                     H, w2t, b2, offsets, tile_pre, slot_tok2, O);
  hipLaunchKernelGGL(combine_kernel, dim3(NTOK / 4), dim3(256), 0, stream,
                     O, tok_g, y);
}

// Round 15
// 268.228 us; speedup vs baseline: 1.0069x; 1.0069x over previous
//
#include <hip/hip_runtime.h>
#include <math.h>

#define NTOK 16384
#define DDIM 512
#define MDIM 1024
#define NEXP 8
#define BKW 32       // K-step in shorts; LDS row = 64 bytes
#define TMAX 264     // max row-tiles across experts: 256 + 8 partial

typedef __attribute__((ext_vector_type(8))) short short8;
typedef __attribute__((ext_vector_type(4))) float floatx4;

__device__ inline unsigned short f2bf(float f){
  union { float f; unsigned int u; } v; v.f = f;
  unsigned int u = v.u;
  u += ((u >> 16) & 1u) + 0x7fffu;   // round-to-nearest-even
  return (unsigned short)(u >> 16);
}

__device__ inline float bf2f(unsigned short s){
  union { unsigned int u; float f; } v;
  v.u = ((unsigned int)s) << 16;
  return v.f;
}

// branch-free erf-based gelu, A&S 7.1.26 (|erf err| <= 1.5e-7)
__device__ inline float gelu_fast(float x){
  float u = x * 0.70710678118654752f;
  float a = fabsf(u);
  float t = __builtin_amdgcn_rcpf(fmaf(0.3275911f, a, 1.0f));
  float p = fmaf(1.061405429f, t, -1.453152027f);
  p = fmaf(p, t, 1.421413741f);
  p = fmaf(p, t, -0.284496736f);
  p = fmaf(p, t, 0.254829592f);
  p = p * t;
  float e = __expf(-u * u);
  float erfa = fmaf(-p, e, 1.0f);         // erf(|u|)
  float erfu = copysignf(erfa, u);
  return 0.5f * x * (1.0f + erfu);
}

// async global -> LDS, 16 bytes per lane; lds base must be wave-uniform
__device__ __forceinline__ void gload16(const unsigned short* g, unsigned short* l){
  __builtin_amdgcn_global_load_lds(
      (const __attribute__((address_space(1))) void*)g,
      (__attribute__((address_space(3))) void*)l,
      16, 0, 0);
}

// ---------------- fused prep: W1/W2 transpose+bf16 conv + counts/imp/rank init ----
// grid (32,16,16): z<8 -> W1 (R=512,C=1024)   z>=8 -> W2 (R=1024,C=512)

__global__ void prep_kernel(const float* __restrict__ W1, const float* __restrict__ W2,
                            unsigned short* __restrict__ w1t, unsigned short* __restrict__ w2t,
                            int* __restrict__ counts, float* __restrict__ imp,
                            int* __restrict__ rank){
  __shared__ float tile[32][33];
  int z = blockIdx.z;
  if (z == 0 && blockIdx.x == 0 && blockIdx.y == 0){
    int flat = threadIdx.y * 32 + threadIdx.x;
    if (flat < NEXP){ counts[flat] = 0; imp[flat] = 0.0f; rank[flat] = 0; }
  }
  const float* in; unsigned short* out; int R, C, c0, r0, e;
  if (z < 8){ e = z;     in = W1; out = w1t; R = DDIM; C = MDIM; c0 = blockIdx.x << 5; r0 = blockIdx.y << 5; }
  else      { e = z - 8; in = W2; out = w2t; R = MDIM; C = DDIM; c0 = blockIdx.y << 5; r0 = blockIdx.x << 5; }
  const float* src = in + (size_t)e * R * C;
  unsigned short* dst = out + (size_t)e * R * C;
  int tc = threadIdx.x;   // 0..31
  int tr = threadIdx.y;   // 0..7
  #pragma unroll
  for (int i = 0; i < 32; i += 8)
    tile[tr + i][tc] = src[(size_t)(r0 + tr + i) * C + c0 + tc];
  __syncthreads();
  #pragma unroll
  for (int i = 0; i < 32; i += 8)
    dst[(size_t)(c0 + tr + i) * R + r0 + tc] = f2bf(tile[tc][tr + i]);
}

// ---------------- fused gating + x->bf16 conversion ----------------

__global__ __launch_bounds__(256)
void gating_kernel(const float* __restrict__ x,
                   const float* __restrict__ wg,
                   unsigned short* __restrict__ xb,
                   int* __restrict__ tok_e, float* __restrict__ tok_g,
                   int* __restrict__ counts, float* __restrict__ imp){
  __shared__ int   lcnt[NEXP];
  __shared__ float limp[NEXP];
  int t = threadIdx.x;
  if (t < NEXP){ lcnt[t] = 0; limp[t] = 0.0f; }
  __syncthreads();

  int wave = t >> 6;
  int lane = t & 63;

  for (int it = 0; it < 4; it++){
    int n = blockIdx.x * 16 + it * 4 + wave;

    const float4* xp = (const float4*)(x + (size_t)n * DDIM + lane * 8);
    float4 a = xp[0], b = xp[1];
    float xv[8] = {a.x, a.y, a.z, a.w, b.x, b.y, b.z, b.w};

    short8 xo;
    #pragma unroll
    for (int j = 0; j < 8; j++) xo[j] = (short)f2bf(xv[j]);
    *(short8*)(xb + (size_t)n * DDIM + lane * 8) = xo;

    double acc[NEXP];
    #pragma unroll
    for (int e = 0; e < NEXP; e++) acc[e] = 0.0;
    #pragma unroll
    for (int j = 0; j < 8; j++){
      const float* wr = wg + (size_t)(lane * 8 + j) * NEXP;
      #pragma unroll
      for (int e = 0; e < NEXP; e++) acc[e] += (double)xv[j] * (double)wr[e];
    }
    #pragma unroll
    for (int off = 32; off >= 1; off >>= 1){
      #pragma unroll
      for (int e = 0; e < NEXP; e++) acc[e] += __shfl_xor(acc[e], off);
    }
    if (lane == 0){
      int i0 = -1, i1 = -1;
      double l0 = -1e300, l1 = -1e300;
      #pragma unroll
      for (int e = 0; e < NEXP; e++){
        double v = acc[e];
        if (v > l0){ l1 = l0; i1 = i0; l0 = v; i0 = e; }
        else if (v > l1){ l1 = v; i1 = e; }
      }
      float ex = expf((float)(l1 - l0));
      float g0 = 1.0f / (1.0f + ex);
      float g1 = ex / (1.0f + ex);
      tok_e[n * 2]     = i0; tok_e[n * 2 + 1] = i1;
      tok_g[n * 2]     = g0; tok_g[n * 2 + 1] = g1;
      atomicAdd(&lcnt[i0], 1); atomicAdd(&lcnt[i1], 1);
      atomicAdd(&limp[i0], g0); atomicAdd(&limp[i1], g1);
    }
  }
  __syncthreads();
  if (t < NEXP){
    atomicAdd(&counts[t], lcnt[t]);
    atomicAdd(&imp[t], limp[t]);
  }
}

// ---------------- scatter + fused loss/offsets publication ----------------
// slot_tok2[slot] = 2n+k (inverse permutation) -> gemm2 stores O token-major,
// combine becomes pure streaming.

__global__ __launch_bounds__(256)
void scatter_kernel(const int* __restrict__ counts,
                    const float* __restrict__ imp,
                    const int* __restrict__ tok_e,
                    int* __restrict__ rank,
                    int* __restrict__ offsets_g, int* __restrict__ tile_pre_g,
                    int* __restrict__ btok, int* __restrict__ slot_tok2,
                    float* __restrict__ out_loss){
  __shared__ int lcnt[NEXP];
  __shared__ int lbase[NEXP];
  int t = threadIdx.x;
  if (t < NEXP) lcnt[t] = 0;
  __syncthreads();

  int n = blockIdx.x * 256 + t;
  int e0 = tok_e[n * 2], e1 = tok_e[n * 2 + 1];
  int r0 = atomicAdd(&lcnt[e0], 1);
  int r1 = atomicAdd(&lcnt[e1], 1);
  __syncthreads();
  if (t < NEXP){
    int offacc = 0;
    #pragma unroll
    for (int e = 0; e < NEXP; e++){ int c = counts[e]; if (e < t) offacc += c; }
    lbase[t] = offacc + atomicAdd(&rank[t], lcnt[t]);
  }
  __syncthreads();
  int s0 = lbase[e0] + r0;
  int s1 = lbase[e1] + r1;
  btok[s0] = n;
  btok[s1] = n;
  slot_tok2[s0] = n * 2;
  slot_tok2[s1] = n * 2 + 1;

  // block 0, wave 0: loss + publish offsets/tile_pre
  if (blockIdx.x == 0 && t < 64){
    int l = t;
    int   c  = (l < NEXP) ? counts[l] : 0;
    float im = (l < NEXP) ? imp[l]    : 0.0f;
    int   tl = (c + 127) >> 7;
    int poff = 0, ptl = 0, tot = 0, tott = 0;
    double si = 0, si2 = 0, sl = 0, sl2 = 0;
    #pragma unroll
    for (int e = 0; e < NEXP; e++){
      int   ce = __shfl(c, e);
      int   te = __shfl(tl, e);
      float ie = __shfl(im, e);
      if (e < l){ poff += ce; ptl += te; }
      tot += ce; tott += te;
      si += (double)ie; si2 += (double)ie * ie;
      sl += (double)ce; sl2 += (double)ce * ce;
    }
    if (l < NEXP){ offsets_g[l] = poff; tile_pre_g[l] = ptl; }
    if (l == 0){
      offsets_g[NEXP] = tot; tile_pre_g[NEXP] = tott;
      double mi = si / 8.0, ml = sl / 8.0;
      double vi = (si2 - 8.0 * mi * mi) / 7.0;
      double vl = (sl2 - 8.0 * ml * ml) / 7.0;
      *out_loss = (float)(0.01 * (vi / (mi * mi + 1e-10) + vl / (ml * ml + 1e-10)));
    }
  }
}

// ------- expert GEMMs: 128x128 tile, 8 waves (512 thr), depth-2 counted vmcnt -------
// R9 exact config (best measured: gemm1 67.0us): 3 LDS buffers; step k:
//   {ds_read frags(buf k%3); STAGE(k+2 -> buf (k+2)%3); MFMA; vmcnt(2); s_barrier}
// Fully unrolled; setprio around MFMA; XOR chunk-swizzle both-sides; contiguous-tt
// XCD map; __launch_bounds__(512,6) (the only validated bound at 512 threads —
// (512,8) hung the GPU in R12/R13). Session verdicts: depth-2 counted vmcnt +9%,
// 8-wave +13%, XCD-map FETCH 53->27MB; drain-0/interleave/BK64/128x256/2-buf all
// null or worse. Both pipes <25% util at this point — further gains require the
// 256^2 8-phase deep pipeline (sync-structure rewrite; needs race screening).

__global__ __launch_bounds__(512, 6)
void gemm1_kernel(const unsigned short* __restrict__ xb,
                  const unsigned short* __restrict__ w1t,   // [E][M][D]
                  const float* __restrict__ b1,             // [E][M]
                  const int* __restrict__ offsets,
                  const int* __restrict__ tile_pre,
                  const int* __restrict__ btok,
                  unsigned short* __restrict__ H){          // [slot][M]
  int b = blockIdx.x;                  // grid = 8*TMAX
  int L = (b & 7) * TMAX + (b >> 3);   // contiguous logical chunk per XCD
  int ct = L & 7;                      // column tile 0..7
  int tt = L >> 3;                     // row tile
  if (tt >= tile_pre[NEXP]) return;
  int e = 0;
  while (tt >= tile_pre[e + 1]) e++;
  int rt = tt - tile_pre[e];
  int off = offsets[e];
  int cnt = offsets[e + 1] - off;
  int r0 = rt << 7;

  __shared__ unsigned short As[3 * 128 * BKW];
  __shared__ unsigned short Bs[3 * 128 * BKW];

  int t = threadIdx.x;
  int w = t >> 6;                         // 0..7
  int l = t & 63;
  int g = (l & 3) ^ ((l >> 3) & 3);       // pre-swizzled source chunk

  const unsigned short* apt;
  {
    int ra = r0 + w * 16 + (l >> 2);  if (ra >= cnt) ra = cnt - 1;
    apt = xb + (size_t)btok[off + ra] * DDIM + g * 8;
  }
  const unsigned short* bpt = w1t + ((size_t)e * MDIM + (ct << 7) + w * 16 + (l >> 2)) * DDIM + g * 8;

  int wr = (w >> 1) << 5;                 // 0,32,64,96
  int wc = (w & 1) << 6;                  // 0,64
  int lm = l & 15;
  int lq = l >> 4;
  int swz = (lm >> 1) & 3;

  int aoff[2], boff[4];
  #pragma unroll
  for (int i = 0; i < 2; i++) aoff[i] = (wr + i * 16 + lm) * BKW + ((lq ^ swz) << 3);
  #pragma unroll
  for (int j = 0; j < 4; j++) boff[j] = (wc + j * 16 + lm) * BKW + ((lq ^ swz) << 3);

  floatx4 acc[2][4] = {};

  #define STAGE1(K0, CB) {                                   \
    gload16(apt + (K0), As + (CB) * 4096 + w * 512);         \
    gload16(bpt + (K0), Bs + (CB) * 4096 + w * 512);         \
  }
  #define READ1(CB) {                                        \
    const unsigned short* Ac = As + (CB) * 4096;             \
    const unsigned short* Bc = Bs + (CB) * 4096;             \
    _Pragma("unroll")                                        \
    for (int i = 0; i < 2; i++) af[i]  = *(const short8*)(Ac + aoff[i]); \
    _Pragma("unroll")                                        \
    for (int j = 0; j < 4; j++) bfr[j] = *(const short8*)(Bc + boff[j]); \
  }
  #define MFMA1 {                                            \
    _Pragma("unroll")                                        \
    for (int i = 0; i < 2; i++)                              \
      _Pragma("unroll")                                      \
      for (int j = 0; j < 4; j++)                            \
        acc[i][j] = __builtin_amdgcn_mfma_f32_16x16x32_bf16(af[i], bfr[j], acc[i][j], 0, 0, 0); \
  }
  #define WAITBAR(N) {                                       \
    asm volatile("s_waitcnt vmcnt(" #N ")" ::: "memory");    \
    __builtin_amdgcn_sched_barrier(0);                       \
    __builtin_amdgcn_s_barrier();                            \
    __builtin_amdgcn_sched_barrier(0);                       \
  }

  const int NK = DDIM / BKW;             // 16
  STAGE1(0, 0);
  STAGE1(BKW, 1);
  WAITBAR(2);                            // buf0 ready; STAGE(1) in flight
  #pragma unroll
  for (int k = 0; k < NK; k++){
    const int cur = k % 3;               // compile-time after unroll
    short8 af[2], bfr[4];
    READ1(cur);
    if (k < NK - 2) STAGE1((k + 2) * BKW, (k + 2) % 3);
    __builtin_amdgcn_s_setprio(1);
    MFMA1;
    __builtin_amdgcn_s_setprio(0);
    if (k < NK - 2){ WAITBAR(2); }       // retire STAGE(k+1); STAGE(k+2) stays out
    else if (k == NK - 2){ WAITBAR(0); } // only STAGE(NK-1) outstanding
    // k == NK-1: no barrier
  }
  #undef STAGE1
  #undef READ1
  #undef MFMA1
  #undef WAITBAR

  const float* bias = b1 + e * MDIM + (ct << 7);
  #pragma unroll
  for (int i = 0; i < 2; i++){
    int rbase = wr + i * 16 + lq * 4;
    #pragma unroll
    for (int j = 0; j < 4; j++){
      int cc = wc + j * 16 + lm;
      float bv = bias[cc];
      #pragma unroll
      for (int r = 0; r < 4; r++){
        int row = r0 + rbase + r;
        if (row < cnt){
          float v = acc[i][j][r] + bv;
          H[(size_t)(off + row) * MDIM + (ct << 7) + cc] = f2bf(gelu_fast(v));
        }
      }
    }
  }
}

__global__ __launch_bounds__(512, 6)
void gemm2_kernel(const unsigned short* __restrict__ H,    // [slot][M]
                  const unsigned short* __restrict__ w2t,  // [E][D][M]
                  const float* __restrict__ b2,            // [E][D]
                  const int* __restrict__ offsets,
                  const int* __restrict__ tile_pre,
                  const int* __restrict__ slot_tok2,
                  unsigned short* __restrict__ O){         // [2n+k][D] bf16, token-major
  int b = blockIdx.x;                        // grid = 4*TMAX = 8*(TMAX/2)
  int L = (b & 7) * (TMAX / 2) + (b >> 3);   // contiguous logical chunk per XCD
  int ct = L & 3;                            // column tile 0..3
  int tt = L >> 2;                           // row tile
  if (tt >= tile_pre[NEXP]) return;
  int e = 0;
  while (tt >= tile_pre[e + 1]) e++;
  int rt = tt - tile_pre[e];
  int off = offsets[e];
  int cnt = offsets[e + 1] - off;
  int r0 = rt << 7;

  __shared__ unsigned short As[3 * 128 * BKW];
  __shared__ unsigned short Bs[3 * 128 * BKW];

  int t = threadIdx.x;
  int w = t >> 6;
  int l = t & 63;
  int g = (l & 3) ^ ((l >> 3) & 3);

  const unsigned short* apt;
  {
    int ra = r0 + w * 16 + (l >> 2);  if (ra >= cnt) ra = cnt - 1;
    apt = H + (size_t)(off + ra) * MDIM + g * 8;
  }
  const unsigned short* bpt = w2t + ((size_t)e * DDIM + (ct << 7) + w * 16 + (l >> 2)) * MDIM + g * 8;

  int wr = (w >> 1) << 5;
  int wc = (w & 1) << 6;
  int lm = l & 15;
  int lq = l >> 4;
  int swz = (lm >> 1) & 3;

  int aoff[2], boff[4];
  #pragma unroll
  for (int i = 0; i < 2; i++) aoff[i] = (wr + i * 16 + lm) * BKW + ((lq ^ swz) << 3);
  #pragma unroll
  for (int j = 0; j < 4; j++) boff[j] = (wc + j * 16 + lm) * BKW + ((lq ^ swz) << 3);

  floatx4 acc[2][4] = {};

  #define STAGE2(K0, CB) {                                   \
    gload16(apt + (K0), As + (CB) * 4096 + w * 512);         \
    gload16(bpt + (K0), Bs + (CB) * 4096 + w * 512);         \
  }
  #define READ2(CB) {                                        \
    const unsigned short* Ac = As + (CB) * 4096;             \
    const unsigned short* Bc = Bs + (CB) * 4096;             \
    _Pragma("unroll")                                        \
    for (int i = 0; i < 2; i++) af[i]  = *(const short8*)(Ac + aoff[i]); \
    _Pragma("unroll")                                        \
    for (int j = 0; j < 4; j++) bfr[j] = *(const short8*)(Bc + boff[j]); \
  }
  #define MFMA2 {                                            \
    _Pragma("unroll")                                        \
    for (int i = 0; i < 2; i++)                              \
      _Pragma("unroll")                                      \
      for (int j = 0; j < 4; j++)                            \
        acc[i][j] = __builtin_amdgcn_mfma_f32_16x16x32_bf16(af[i], bfr[j], acc[i][j], 0, 0, 0); \
  }
  #define WAITBAR2(N) {                                      \
    asm volatile("s_waitcnt vmcnt(" #N ")" ::: "memory");    \
    __builtin_amdgcn_sched_barrier(0);                       \
    __builtin_amdgcn_s_barrier();                            \
    __builtin_amdgcn_sched_barrier(0);                       \
  }

  const int NK = MDIM / BKW;             // 32
  STAGE2(0, 0);
  STAGE2(BKW, 1);
  WAITBAR2(2);
  #pragma unroll
  for (int k = 0; k < NK; k++){
    const int cur = k % 3;
    short8 af[2], bfr[4];
    READ2(cur);
    if (k < NK - 2) STAGE2((k + 2) * BKW, (k + 2) % 3);
    __builtin_amdgcn_s_setprio(1);
    MFMA2;
    __builtin_amdgcn_s_setprio(0);
    if (k < NK - 2){ WAITBAR2(2); }
    else if (k == NK - 2){ WAITBAR2(0); }
  }
  #undef STAGE2
  #undef READ2
  #undef MFMA2
  #undef WAITBAR2

  const float* bias = b2 + e * DDIM + (ct << 7);
  #pragma unroll
  for (int i = 0; i < 2; i++){
    int rbase = wr + i * 16 + lq * 4;
    #pragma unroll
    for (int r = 0; r < 4; r++){
      int row = r0 + rbase + r;
      if (row < cnt){
        int t2 = slot_tok2[off + row];     // token-major destination row
        #pragma unroll
        for (int j = 0; j < 4; j++){
          int cc = wc + j * 16 + lm;
          O[(size_t)t2 * DDIM + (ct << 7) + cc] = f2bf(acc[i][j][r] + bias[cc]);
        }
      }
    }
  }
}

// ------- streaming combine: y[n] = g0*O[2n] + g1*O[2n+1], fully sequential -------

__global__ __launch_bounds__(256)
void combine_kernel(const unsigned short* __restrict__ O,
                    const float* __restrict__ tok_g,
                    float* __restrict__ y){
  int wave = threadIdx.x >> 6;
  int lane = threadIdx.x & 63;
  int n = blockIdx.x * 4 + wave;
  float g0 = tok_g[n * 2], g1 = tok_g[n * 2 + 1];
  short8 a = *(const short8*)(O + (size_t)(n * 2)     * DDIM + lane * 8);
  short8 b = *(const short8*)(O + (size_t)(n * 2 + 1) * DDIM + lane * 8);
  float4 o0, o1;
  float* po0 = (float*)&o0;
  float* po1 = (float*)&o1;
  #pragma unroll
  for (int j = 0; j < 4; j++){
    po0[j] = g0 * bf2f((unsigned short)a[j]) + g1 * bf2f((unsigned short)b[j]);
    po1[j] = g0 * bf2f((unsigned short)a[j + 4]) + g1 * bf2f((unsigned short)b[j + 4]);
  }
  float4* yp = (float4*)(y + (size_t)n * DDIM + lane * 8);
  yp[0] = o0;
  yp[1] = o1;
}

// ---------------- launch ----------------

extern "C" void kernel_launch(void* const* d_in, const int* in_sizes, int n_in,
                              void* d_out, int out_size, void* d_ws, size_t ws_size,
                              hipStream_t stream){
  const float* x  = (const float*)d_in[0];
  const float* wg = (const float*)d_in[1];
  const float* W1 = (const float*)d_in[2];
  const float* b1 = (const float*)d_in[3];
  const float* W2 = (const float*)d_in[4];
  const float* b2 = (const float*)d_in[5];
  float* y = (float*)d_out;

  char* ws = (char*)d_ws;
  size_t o = 0;
  auto alloc = [&](size_t bytes)->char*{
    char* p = ws + o;
    o += (bytes + 255) & ~(size_t)255;
    return p;
  };
  unsigned short* xb   = (unsigned short*)alloc((size_t)NTOK * DDIM * 2);
  unsigned short* w1t  = (unsigned short*)alloc((size_t)NEXP * MDIM * DDIM * 2);
  unsigned short* w2t  = (unsigned short*)alloc((size_t)NEXP * DDIM * MDIM * 2);
  unsigned short* H    = (unsigned short*)alloc((size_t)NTOK * 2 * MDIM * 2);
  unsigned short* O    = (unsigned short*)alloc((size_t)NTOK * 2 * DDIM * 2);
  int*   btok     = (int*)  alloc((size_t)NTOK * 2 * 4);
  int*   slot_tok2= (int*)  alloc((size_t)NTOK * 2 * 4);
  int*   tok_e    = (int*)  alloc((size_t)NTOK * 2 * 4);
  float* tok_g    = (float*)alloc((size_t)NTOK * 2 * 4);
  int*   counts   = (int*)  alloc(64);
  float* imp      = (float*)alloc(64);
  int*   rank     = (int*)  alloc(64);
  int*   offsets  = (int*)  alloc(64);
  int*   tile_pre = (int*)  alloc(64);

  hipLaunchKernelGGL(prep_kernel, dim3(32, 16, 16), dim3(32, 8), 0, stream,
                     W1, W2, w1t, w2t, counts, imp, rank);
  hipLaunchKernelGGL(gating_kernel, dim3(NTOK / 16), dim3(256), 0, stream,
                     x, wg, xb, tok_e, tok_g, counts, imp);
  hipLaunchKernelGGL(scatter_kernel, dim3(NTOK / 256), dim3(256), 0, stream,
                     counts, imp, tok_e, rank, offsets, tile_pre,
                     btok, slot_tok2, y + (size_t)NTOK * DDIM);
  hipLaunchKernelGGL(gemm1_kernel, dim3(TMAX * 8), dim3(512), 0, stream,
                     xb, w1t, b1, offsets, tile_pre, btok, H);
  hipLaunchKernelGGL(gemm2_kernel, dim3(TMAX * 4), dim3(512), 0, stream,
                     H, w2t, b2, offsets, tile_pre, slot_tok2, O);
  hipLaunchKernelGGL(combine_kernel, dim3(NTOK / 4), dim3(256), 0, stream,
                     O, tok_g, y);
}